// Round 9
// baseline (9836.580 us; speedup 1.0000x reference)
//
#include <hip/hip_runtime.h>

#define NB 64
#define NPTS 500
#define ND 2048
#define NK 10
#define NITERS 10
#define FEPS 1e-6f
#define NPG 8                // point groups (blocks per batch)
#define PPB 64               // points per block (8 waves * 2 pts * 4 sweeps)
#define ACCN (4 * NK * 512)  // component-plane LDS accumulator floats (20480 = 80 KB)

// ---------------------------------------------------------------------------
// init: block per (b,k): copy f[b,k,:] -> cent, compute cnorm, zero sums row
// (atomic layout only), zero counts.
// ---------------------------------------------------------------------------
__global__ __launch_bounds__(256) void init_kernel(const float* __restrict__ f,
                                                   float* __restrict__ cent,
                                                   float* __restrict__ cnorm,
                                                   int* __restrict__ counts,
                                                   float* __restrict__ sums,
                                                   int useAtomic)
{
    const int bid = blockIdx.x;          // 0..639
    const int b = bid / NK, k = bid - b * NK;
    const int tid = threadIdx.x, wave = tid >> 6, lane = tid & 63;

    const float4* src = (const float4*)(f + ((size_t)b * NPTS + k) * ND);
    float4* dst = (float4*)cent + (size_t)bid * 512;
    float4* srow = (float4*)sums + (size_t)bid * 512;
    const float4 z4 = make_float4(0.f, 0.f, 0.f, 0.f);

    float nrm = 0.f;
    for (int i = tid; i < 512; i += 256) {
        float4 v = src[i];
        dst[i] = v;
        nrm += v.x * v.x + v.y * v.y + v.z * v.z + v.w * v.w;
        if (useAtomic) srow[i] = z4;
    }
#pragma unroll
    for (int off = 32; off > 0; off >>= 1) nrm += __shfl_xor(nrm, off, 64);
    __shared__ float red[4];
    if (lane == 0) red[wave] = nrm;
    __syncthreads();
    if (tid == 0) cnorm[bid] = red[0] + red[1] + red[2] + red[3];

    int gid = bid * 256 + tid;
    if (gid < NITERS * NB * NK) counts[gid] = 0;
}

// ---------------------------------------------------------------------------
// fused assign+update: grid (NPG=8 point-groups, NB), 512 threads (8 waves),
// 2 blocks/CU (80 KB LDS), target 4 waves/SIMD.
// Each wave: 2 points/sweep, 4 sweeps. Live set ~114 VGPR (R0+R1 rows = 64)
// -- fits the compiler's LDS-occupancy-implied 128-VGPR cap with NO spill
// (R6 post-mortem: 4 pts/sweep = ~200 live -> spilled ~850 MB/dispatch HBM).
// All 20 dot partials reduced in ONE interleaved butterfly (20 indep chains).
// Rows (kept in registers) are LDS-atomic-accumulated into component planes,
// flushed as deterministic per-block partials or global fp atomics.
// ---------------------------------------------------------------------------
__global__ __launch_bounds__(512, 2) void fused_kernel(const float* __restrict__ f,
                                                       const float* __restrict__ cent,
                                                       const float* __restrict__ cnorm,
                                                       int* __restrict__ assignG,
                                                       int* __restrict__ counts_it,
                                                       float* __restrict__ sums,
                                                       float* __restrict__ partial,
                                                       int useAtomic)
{
    __shared__ float accP[ACCN];               // [4 comp][NK][512] = 80 KB

    const int b = blockIdx.y, pg = blockIdx.x;
    const int tid = threadIdx.x, wave = tid >> 6, lane = tid & 63;

    for (int i = tid; i < ACCN; i += 512) accP[i] = 0.f;
    __syncthreads();

    const float4* fb4 = (const float4*)(f + (size_t)b * NPTS * ND) + (size_t)pg * PPB * 512;
    const float4* c4  = (const float4*)(cent + (size_t)b * NK * ND);
    const int lim = NPTS - pg * PPB;           // valid local points (52 for pg=7)

    float cn[NK];
#pragma unroll
    for (int k = 0; k < NK; ++k) cn[k] = cnorm[b * NK + k];

    for (int s = 0; s < 4; ++s) {
        const int l0 = s * 16 + wave * 2;      // this wave's 2 local points
        const int m0 = (l0     < lim) ? l0     : lim - 1;  // clamp (guarded below)
        const int m1 = (l0 + 1 < lim) ? l0 + 1 : lim - 1;

        // ---- load 2 rows (32+32 VGPRs) ----
        float4 R0[8], R1[8];
        {
            const float4* r0 = fb4 + (size_t)m0 * 512;
            const float4* r1 = fb4 + (size_t)m1 * 512;
#pragma unroll
            for (int j = 0; j < 8; ++j) {
                R0[j] = r0[j * 64 + lane];
                R1[j] = r1[j * 64 + lane];
            }
        }

        // ---- dots: 8 FMA per centroid float4 load ----
        float d0[NK], d1[NK];
#pragma unroll
        for (int k = 0; k < NK; ++k) { d0[k] = 0.f; d1[k] = 0.f; }
#pragma unroll
        for (int k = 0; k < NK; ++k) {
#pragma unroll
            for (int j = 0; j < 8; ++j) {
                float4 c = c4[k * 512 + j * 64 + lane];
                d0[k] = fmaf(R0[j].x, c.x, d0[k]); d0[k] = fmaf(R0[j].y, c.y, d0[k]);
                d0[k] = fmaf(R0[j].z, c.z, d0[k]); d0[k] = fmaf(R0[j].w, c.w, d0[k]);
                d1[k] = fmaf(R1[j].x, c.x, d1[k]); d1[k] = fmaf(R1[j].y, c.y, d1[k]);
                d1[k] = fmaf(R1[j].z, c.z, d1[k]); d1[k] = fmaf(R1[j].w, c.w, d1[k]);
            }
        }

        // ---- one interleaved butterfly: 20 independent 6-step chains ----
#pragma unroll
        for (int off = 1; off < 64; off <<= 1)
#pragma unroll
            for (int k = 0; k < NK; ++k) {
                d0[k] += __shfl_xor(d0[k], off, 64);
                d1[k] += __shfl_xor(d1[k], off, 64);
            }

        // ---- argmin (redundant across lanes; strict < = first-min, matching
        //      jnp.argmin), guarded writes + LDS accumulation ----
        int a0 = 0, a1 = 0;
        float s0 = 0.5f * cn[0] - d0[0], s1 = 0.5f * cn[0] - d1[0];
#pragma unroll
        for (int k = 1; k < NK; ++k) {
            float t0 = 0.5f * cn[k] - d0[k];
            float t1 = 0.5f * cn[k] - d1[k];
            if (t0 < s0) { s0 = t0; a0 = k; }
            if (t1 < s1) { s1 = t1; a1 = k; }
        }
        const bool v0 = (l0 < lim), v1 = (l0 + 1 < lim);
        if (lane == 0) {
            if (v0) { assignG[b * NPTS + pg * PPB + l0]     = a0;
                      atomicAdd(&counts_it[b * NK + a0], 1); }
            if (v1) { assignG[b * NPTS + pg * PPB + l0 + 1] = a1;
                      atomicAdd(&counts_it[b * NK + a1], 1); }
        }
        if (v0) {
#pragma unroll
            for (int j = 0; j < 8; ++j) {
                int q = a0 * 512 + j * 64 + lane;   // bank = lane%32: free 2-way
                atomicAdd(&accP[0 * 5120 + q], R0[j].x);
                atomicAdd(&accP[1 * 5120 + q], R0[j].y);
                atomicAdd(&accP[2 * 5120 + q], R0[j].z);
                atomicAdd(&accP[3 * 5120 + q], R0[j].w);
            }
        }
        if (v1) {
#pragma unroll
            for (int j = 0; j < 8; ++j) {
                int q = a1 * 512 + j * 64 + lane;
                atomicAdd(&accP[0 * 5120 + q], R1[j].x);
                atomicAdd(&accP[1 * 5120 + q], R1[j].y);
                atomicAdd(&accP[2 * 5120 + q], R1[j].z);
                atomicAdd(&accP[3 * 5120 + q], R1[j].w);
            }
        }
    }

    __syncthreads();

    if (useAtomic) {
        for (int e = tid; e < ACCN; e += 512) {
            int c = e / 5120, r = e - c * 5120;
            int k = r >> 9, q = r & 511;
            atomicAdd(&sums[((size_t)(b * NK + k)) * ND + q * 4 + c], accP[e]);
        }
    } else {
        float4* prow = (float4*)partial + ((size_t)(b * NPG + pg)) * NK * 512;
        for (int idx = tid; idx < NK * 512; idx += 512) {
            float4 v = make_float4(accP[0 * 5120 + idx], accP[1 * 5120 + idx],
                                   accP[2 * 5120 + idx], accP[3 * 5120 + idx]);
            prow[idx] = v;
        }
    }
}

// ---------------------------------------------------------------------------
// finalize: block per (b,k): cent = sum/max(cnt,1); cnorm = ||cent||^2.
// Atomic layout: also re-zero sums row for next iteration.
// ---------------------------------------------------------------------------
__global__ __launch_bounds__(256) void finalize_kernel(float* __restrict__ cent,
                                                       float* __restrict__ cnorm,
                                                       const int* __restrict__ counts_it,
                                                       float* __restrict__ sums,
                                                       const float* __restrict__ partial,
                                                       int useAtomic)
{
    const int bid = blockIdx.x;          // b*NK + k
    const int b = bid / NK, k = bid - b * NK;
    const int tid = threadIdx.x, wave = tid >> 6, lane = tid & 63;

    const float cnt = fmaxf((float)counts_it[bid], 1.f);
    float4* crow = (float4*)cent + (size_t)bid * 512;
    float4* srow = (float4*)sums + (size_t)bid * 512;
    const float4* p4 = (const float4*)partial;
    const float4 z4 = make_float4(0.f, 0.f, 0.f, 0.f);

    float nrm = 0.f;
    for (int i = tid; i < 512; i += 256) {
        float4 s;
        if (useAtomic) {
            s = srow[i];
            srow[i] = z4;
        } else {
            s = z4;
#pragma unroll
            for (int pg = 0; pg < NPG; ++pg) {
                float4 pv = p4[((size_t)(b * NPG + pg) * NK + k) * 512 + i];
                s.x += pv.x; s.y += pv.y; s.z += pv.z; s.w += pv.w;
            }
        }
        float4 cv = make_float4(s.x / cnt, s.y / cnt, s.z / cnt, s.w / cnt);
        crow[i] = cv;
        nrm += cv.x * cv.x + cv.y * cv.y + cv.z * cv.z + cv.w * cv.w;
    }
#pragma unroll
    for (int off = 32; off > 0; off >>= 1) nrm += __shfl_xor(nrm, off, 64);
    __shared__ float red[4];
    if (lane == 0) red[wave] = nrm;
    __syncthreads();
    if (tid == 0) cnorm[bid] = red[0] + red[1] + red[2] + red[3];
}

// ---------------------------------------------------------------------------
// gem: thread per (b,d); powed cluster means ^ (1/p); empty -> centroid.
// ---------------------------------------------------------------------------
__global__ __launch_bounds__(256) void gem_kernel(const float* __restrict__ f,
                                                  const float* __restrict__ p_ptr,
                                                  const int* __restrict__ assign,
                                                  const int* __restrict__ counts_it,
                                                  const float* __restrict__ cent,
                                                  float* __restrict__ out)
{
    __shared__ int sAsn[NPTS];
    const int b = blockIdx.y;
    const int d = blockIdx.x * 256 + threadIdx.x;
    const float p = p_ptr[0];
    for (int i = threadIdx.x; i < NPTS; i += 256) sAsn[i] = assign[b * NPTS + i];
    __syncthreads();

    float acc[NK];
#pragma unroll
    for (int k = 0; k < NK; ++k) acc[k] = 0.f;

    const float* fp = f + (size_t)b * NPTS * ND + d;
#pragma unroll 2
    for (int n = 0; n < NPTS; ++n) {
        float v  = fp[(size_t)n * ND];
        float x  = fmaxf(v, FEPS);
        float pw = __expf(p * __logf(x));
        int a = sAsn[n];
#pragma unroll
        for (int k = 0; k < NK; ++k) acc[k] += (a == k) ? pw : 0.f;
    }

    const float invp = 1.f / p;
#pragma unroll
    for (int k = 0; k < NK; ++k) {
        int cnt = counts_it[b * NK + k];
        float res;
        if (cnt > 0) {
            float mean = acc[k] / (float)cnt;
            res = __expf(invp * __logf(mean));
        } else {
            res = cent[((size_t)b * NK + k) * ND + d];
        }
        out[((size_t)b * NK + k) * ND + d] = res;
    }
}

// ---------------------------------------------------------------------------
extern "C" void kernel_launch(void* const* d_in, const int* in_sizes, int n_in,
                              void* d_out, int out_size, void* d_ws, size_t ws_size,
                              hipStream_t stream)
{
    (void)in_sizes; (void)n_in; (void)out_size;

    const float* f = (const float*)d_in[0];
    const float* p = (const float*)d_in[1];
    float* out = (float*)d_out;

    const size_t centN = (size_t)NB * NK * ND;           // 1,310,720 floats
    float* cent  = (float*)d_ws;
    float* cnorm = cent + centN;                         // 640
    int*   counts = (int*)(cnorm + NB * NK);             // 6400
    int*   assign = counts + NITERS * NB * NK;           // 32000
    float* big    = (float*)(assign + NB * NPTS);
    size_t baseB  = (size_t)((char*)big - (char*)d_ws);

    // deterministic per-block partials if ws allows (~42 MB), else fp atomics
    const int useAtomic = (ws_size >= baseB + (size_t)NPG * centN * sizeof(float)) ? 0 : 1;
    float* sums    = big;   // atomic layout
    float* partial = big;   // partial layout

    init_kernel<<<NB * NK, 256, 0, stream>>>(f, cent, cnorm, counts, sums, useAtomic);
    for (int it = 0; it < NITERS; ++it) {
        fused_kernel<<<dim3(NPG, NB), 512, 0, stream>>>(
            f, cent, cnorm, assign, counts + it * NB * NK, sums, partial, useAtomic);
        finalize_kernel<<<NB * NK, 256, 0, stream>>>(
            cent, cnorm, counts + it * NB * NK, sums, partial, useAtomic);
    }
    gem_kernel<<<dim3(ND / 256, NB), 256, 0, stream>>>(
        f, p, assign, counts + (NITERS - 1) * NB * NK, cent, out);
}